// Round 4
// baseline (497.378 us; speedup 1.0000x reference)
//
#include <hip/hip_runtime.h>
#include <cstddef>

// ============================================================================
// MaskedMultiHeadAttention (B=4,S=2048,DM=1024,H=16,HD=64), faithful to ref:
//   softmax over the QUERY axis (axis=2), then /sqrt(HD); mask is a no-op.
// Round 4: attn retiled to 32x32x16 MFMA with Q frags + P in REGISTERS
// (shfl-based C->B layout transpose, no P LDS roundtrip), per-wave k-slice
// partial O^T reduced once at end; stats retiled the same way; QKV proj in
// one dispatch (ss applied in attn). 5 launches.
// ============================================================================

typedef unsigned short u16t;
typedef __attribute__((ext_vector_type(8))) short short8;
typedef __attribute__((ext_vector_type(4))) float floatx4;
typedef __attribute__((ext_vector_type(16))) float floatx16;

#define MFMA16(a, b, c) __builtin_amdgcn_mfma_f32_16x16x32_bf16((a), (b), (c), 0, 0, 0)
#define MFMA32(a, b, c) __builtin_amdgcn_mfma_f32_32x32x16_bf16((a), (b), (c), 0, 0, 0)
#define GLDS16(g, l)                                                        \
  __builtin_amdgcn_global_load_lds(                                         \
      (const __attribute__((address_space(1))) unsigned int*)(g),           \
      (__attribute__((address_space(3))) unsigned int*)(l), 16, 0, 0)

#if __has_builtin(__builtin_amdgcn_exp2f)
#define EXP2(x) __builtin_amdgcn_exp2f(x)
#else
#define EXP2(x) __expf(0.69314718f * (x))
#endif

static __device__ __forceinline__ u16t f2bf(float f) {
  union { float f; unsigned u; } v; v.f = f;
  unsigned r = v.u + 0x7FFFu + ((v.u >> 16) & 1u);  // RNE
  return (u16t)(r >> 16);
}
// Pack two f32 -> two bf16 (round-half-up) in one v_perm: hi<<16 | lo.
static __device__ __forceinline__ unsigned pack2(float hi, float lo) {
  union { float f; unsigned u; } a, b; a.f = hi; b.f = lo;
  return __builtin_amdgcn_perm(a.u + 0x8000u, b.u + 0x8000u, 0x07060302u);
}

// XOR swizzle within a 64/128-elem row block (8-elem groups).
static __device__ __forceinline__ int swz(int row, int col) {
  return (((col >> 3) ^ (row & 7)) << 3) | (col & 7);
}
// f32 4-elem-group swizzle for the O-reduction scratch (64-col rows).
static __device__ __forceinline__ int sw4(int row, int col) {
  return ((((col >> 2) ^ row) & 15) << 2) | (col & 3);
}

#define SEQ    2048
#define NHEAD  16
#define HDIM   64
#define DMODEL 1024

// ---------------------------------------------------------------------------
// All four W [1024][1024] f32 (in,out) -> WT [n][k-swizzled] bf16, one launch.
__global__ __launch_bounds__(256)
void wt_kernel(const float* __restrict__ W0, const float* __restrict__ W1,
               const float* __restrict__ W2, const float* __restrict__ W3,
               u16t* __restrict__ T0, u16t* __restrict__ T1,
               u16t* __restrict__ T2, u16t* __restrict__ T3) {
  int id = blockIdx.x * 256 + threadIdx.x;  // 2048 blocks
  int wsel = id >> 17;
  int r = id & 131071;
  int n = r & 1023;
  int k0 = (r >> 10) << 3;
  const float* W = wsel == 0 ? W0 : wsel == 1 ? W1 : wsel == 2 ? W2 : W3;
  u16t* T = wsel == 0 ? T0 : wsel == 1 ? T1 : wsel == 2 ? T2 : T3;
  const float* src = W + (size_t)k0 * 1024 + n;
  float f[8];
#pragma unroll
  for (int i = 0; i < 8; ++i) f[i] = src[(size_t)i * 1024];
  uint4 p;
  p.x = pack2(f[1], f[0]); p.y = pack2(f[3], f[2]);
  p.z = pack2(f[5], f[4]); p.w = pack2(f[7], f[6]);
  *(uint4*)&T[(size_t)n * 1024 + (k0 & ~63) + swz(n, k0 & 63)] = p;
}

// ---------------------------------------------------------------------------
// QKV projections, one dispatch (z = 0:Q, 1:K, 2:V). A fp32 staged+converted,
// B = pre-swizzled WT via global_load_lds. 16x16x32 MFMA (m97 pattern).
// z<2: out bf16 swizzled [b,h,s,d] (Q scaled by 1/ln2); z=2: [b,h,d,s].
__global__ __launch_bounds__(256)
void proj_qkv(const float* __restrict__ Aq, const float* __restrict__ Ak,
              const float* __restrict__ Av,
              const u16t* __restrict__ Wq, const u16t* __restrict__ Wk,
              const u16t* __restrict__ Wv,
              const float* __restrict__ Bq, const float* __restrict__ Bk,
              const float* __restrict__ Bv,
              u16t* __restrict__ Oq, u16t* __restrict__ Ok,
              u16t* __restrict__ Ov) {
  constexpr int K = 1024;
  __shared__ __align__(16) u16t lA[128 * 64];
  __shared__ __align__(16) u16t lB[128 * 64];
  const int z = blockIdx.z;
  const float* Ap = z == 0 ? Aq : z == 1 ? Ak : Av;
  const u16t* BT = z == 0 ? Wq : z == 1 ? Wk : Wv;
  const float* bias = z == 0 ? Bq : z == 1 ? Bk : Bv;
  u16t* Cp = z == 0 ? Oq : z == 1 ? Ok : Ov;
  const float qsc = z == 0 ? 1.44269504f : 1.0f;
  const int tid = threadIdx.x;
  const int lane = tid & 63, w = tid >> 6;
  const int wm = w >> 1, wn = w & 1;
  const int lrow = lane & 15, lq = lane >> 4;
  const int m0 = blockIdx.y * 128, n0 = blockIdx.x * 128;

  floatx4 acc[4][4];
#pragma unroll
  for (int i = 0; i < 4; ++i)
#pragma unroll
    for (int j = 0; j < 4; ++j) acc[i][j] = {0.f, 0.f, 0.f, 0.f};

  for (int kb = 0; kb < K; kb += 64) {
#pragma unroll
    for (int i = 0; i < 8; ++i) {
      int e = (i * 256 + tid) * 4;  // element in 128x64 tile
      int r = e >> 6, c = e & 63;
      const float* src = Ap + (size_t)(m0 + r) * K + kb + c;
      uint2 p;
      p.x = pack2(src[1], src[0]);
      p.y = pack2(src[3], src[2]);
      *(uint2*)&lA[r * 64 + swz(r, c)] = p;
    }
#pragma unroll
    for (int i = 0; i < 4; ++i) {
      int chunk = w * 4 + i;
      int off = chunk * 1024 + lane * 16;
      int r = off >> 7, ib = off & 127;
      GLDS16(BT + (size_t)(n0 + r) * K + kb + (ib >> 1), &lB[chunk * 512]);
    }
    __syncthreads();
#pragma unroll
    for (int kk = 0; kk < 2; ++kk) {
      short8 af[4], bfr[4];
#pragma unroll
      for (int t = 0; t < 4; ++t) {
        int ar = wm * 64 + t * 16 + lrow;
        af[t] = *(const short8*)&lA[ar * 64 + swz(ar, kk * 32 + lq * 8)];
      }
#pragma unroll
      for (int t = 0; t < 4; ++t) {
        int br = wn * 64 + t * 16 + lrow;
        bfr[t] = *(const short8*)&lB[br * 64 + swz(br, kk * 32 + lq * 8)];
      }
#pragma unroll
      for (int i = 0; i < 4; ++i)
#pragma unroll
        for (int j = 0; j < 4; ++j)
          acc[i][j] = MFMA16(af[i], bfr[j], acc[i][j]);
    }
    __syncthreads();
  }

  float bvv[4];
#pragma unroll
  for (int j = 0; j < 4; ++j) bvv[j] = bias[n0 + wn * 64 + j * 16 + lrow];
  const int h = (n0 + wn * 64) >> 6;
#pragma unroll
  for (int i = 0; i < 4; ++i) {
#pragma unroll
    for (int r = 0; r < 4; ++r) {
      int rg = m0 + wm * 64 + i * 16 + lq * 4 + r;
      int b = rg >> 11, s = rg & 2047;
      size_t bh = (size_t)(b * NHEAD + h);
#pragma unroll
      for (int j = 0; j < 4; ++j) {
        int cg = n0 + wn * 64 + j * 16 + lrow;
        int d = cg & 63;
        float v = (acc[i][j][r] + bvv[j]) * qsc;
        if (z < 2)
          Cp[(bh * SEQ + s) * HDIM + swz(s, d)] = f2bf(v);
        else
          Cp[(bh * HDIM + d) * SEQ + (s & ~127) + swz(d, s & 127)] = f2bf(v);
      }
    }
  }
}

// ---------------------------------------------------------------------------
// Out projection: A = Hout bf16 swizzled (GLDS), out fp32 flat [m][n].
__global__ __launch_bounds__(256)
void proj_out(const u16t* __restrict__ Ap, const u16t* __restrict__ BT,
              const float* __restrict__ bias, float* __restrict__ Cp) {
  constexpr int K = 1024;
  __shared__ __align__(16) u16t lA[128 * 64];
  __shared__ __align__(16) u16t lB[128 * 64];
  const int tid = threadIdx.x;
  const int lane = tid & 63, w = tid >> 6;
  const int wm = w >> 1, wn = w & 1;
  const int lrow = lane & 15, lq = lane >> 4;
  const int m0 = blockIdx.y * 128, n0 = blockIdx.x * 128;

  floatx4 acc[4][4];
#pragma unroll
  for (int i = 0; i < 4; ++i)
#pragma unroll
    for (int j = 0; j < 4; ++j) acc[i][j] = {0.f, 0.f, 0.f, 0.f};

  for (int kb = 0; kb < K; kb += 64) {
#pragma unroll
    for (int i = 0; i < 4; ++i) {
      int chunk = w * 4 + i;
      int off = chunk * 1024 + lane * 16;
      int r = off >> 7, ib = off & 127;
      GLDS16(Ap + (size_t)(m0 + r) * K + kb + (ib >> 1), &lA[chunk * 512]);
    }
#pragma unroll
    for (int i = 0; i < 4; ++i) {
      int chunk = w * 4 + i;
      int off = chunk * 1024 + lane * 16;
      int r = off >> 7, ib = off & 127;
      GLDS16(BT + (size_t)(n0 + r) * K + kb + (ib >> 1), &lB[chunk * 512]);
    }
    __syncthreads();
#pragma unroll
    for (int kk = 0; kk < 2; ++kk) {
      short8 af[4], bfr[4];
#pragma unroll
      for (int t = 0; t < 4; ++t) {
        int ar = wm * 64 + t * 16 + lrow;
        af[t] = *(const short8*)&lA[ar * 64 + swz(ar, kk * 32 + lq * 8)];
      }
#pragma unroll
      for (int t = 0; t < 4; ++t) {
        int br = wn * 64 + t * 16 + lrow;
        bfr[t] = *(const short8*)&lB[br * 64 + swz(br, kk * 32 + lq * 8)];
      }
#pragma unroll
      for (int i = 0; i < 4; ++i)
#pragma unroll
        for (int j = 0; j < 4; ++j)
          acc[i][j] = MFMA16(af[i], bfr[j], acc[i][j]);
    }
    __syncthreads();
  }

  float bvv[4];
#pragma unroll
  for (int j = 0; j < 4; ++j) bvv[j] = bias[n0 + wn * 64 + j * 16 + lrow];
#pragma unroll
  for (int i = 0; i < 4; ++i)
#pragma unroll
    for (int r = 0; r < 4; ++r) {
      int rg = m0 + wm * 64 + i * 16 + lq * 4 + r;
#pragma unroll
      for (int j = 0; j < 4; ++j) {
        int cg = n0 + wn * 64 + j * 16 + lrow;
        Cp[(size_t)rg * 1024 + cg] = acc[i][j][r] + bvv[j];
      }
    }
}

// ---------------------------------------------------------------------------
// Column-softmax stats, exp2 domain (Q pre-scaled 1/ln2, S' bounded):
//   ss[k] = 1/(8 * sum_q 2^(S'[q,k])).  32x32x16 MFMA, K frags in registers.
// Grid (8,64): block = 256 cols; wave w owns cols [w*64, w*64+64).
__global__ __launch_bounds__(256)
void stats_kernel(const u16t* __restrict__ Qb, const u16t* __restrict__ Kb,
                  float* __restrict__ ss) {
  __shared__ __align__(16) u16t lK[256 * 64];  // 32KB
  __shared__ __align__(16) u16t lQ[128 * 64];  // 16KB
  const int tid = threadIdx.x, lane = tid & 63, w = tid >> 6;
  const int l31 = lane & 31, lh = lane >> 5;
  const int bh = blockIdx.y;
  const int c0 = blockIdx.x * 256;
  const u16t* Kbase = Kb + (size_t)bh * (SEQ * HDIM);
  const u16t* Qbase = Qb + (size_t)bh * (SEQ * HDIM);

#pragma unroll
  for (int i = 0; i < 8; ++i) {
    int c = w * 8 + i;
    GLDS16(Kbase + (size_t)c0 * HDIM + c * 512 + lane * 8, &lK[c * 512]);
  }

  short8 kf[2][4];
  float acc[2][16];
#pragma unroll
  for (int kb = 0; kb < 2; ++kb)
#pragma unroll
    for (int r = 0; r < 16; ++r) acc[kb][r] = 0.f;

  for (int q0 = 0; q0 < SEQ; q0 += 128) {
#pragma unroll
    for (int i = 0; i < 4; ++i) {
      int c = w * 4 + i;
      GLDS16(Qbase + (size_t)q0 * HDIM + c * 512 + lane * 8, &lQ[c * 512]);
    }
    __syncthreads();
    if (q0 == 0) {
#pragma unroll
      for (int kb = 0; kb < 2; ++kb)
#pragma unroll
        for (int t = 0; t < 4; ++t) {
          int r = w * 64 + kb * 32 + l31;
          kf[kb][t] = *(const short8*)&lK[r * 64 + swz(r, t * 16 + lh * 8)];
        }
    }
#pragma unroll
    for (int qb = 0; qb < 4; ++qb) {
      short8 qfr[4];
#pragma unroll
      for (int t = 0; t < 4; ++t) {
        int r = qb * 32 + l31;
        qfr[t] = *(const short8*)&lQ[r * 64 + swz(r, t * 16 + lh * 8)];
      }
#pragma unroll
      for (int kb = 0; kb < 2; ++kb) {
        floatx16 st;
#pragma unroll
        for (int r = 0; r < 16; ++r) st[r] = 0.f;
#pragma unroll
        for (int t = 0; t < 4; ++t) st = MFMA32(kf[kb][t], qfr[t], st);
#pragma unroll
        for (int r = 0; r < 16; ++r) acc[kb][r] += EXP2(st[r]);
      }
    }
    __syncthreads();
  }
  // sum over the 32 q-lanes (lane bits 0..4); both halves reduce separately
#pragma unroll
  for (int kb = 0; kb < 2; ++kb)
#pragma unroll
    for (int r = 0; r < 16; ++r) {
      float v = acc[kb][r];
#pragma unroll
      for (int off = 1; off <= 16; off <<= 1) v += __shfl_xor(v, off);
      acc[kb][r] = v;
    }
  if (l31 == 0) {  // lanes 0 and 32 write (lh selects +4 k offset)
#pragma unroll
    for (int kb = 0; kb < 2; ++kb)
#pragma unroll
      for (int r = 0; r < 16; ++r) {
        int k = c0 + w * 64 + kb * 32 + (r & 3) + 8 * (r >> 2) + 4 * lh;
        ss[(size_t)bh * SEQ + k] = 1.f / (8.f * acc[kb][r]);
      }
  }
}

// ---------------------------------------------------------------------------
// attn: 64-q tile per block. 32x32x16 MFMA. Q frags persistent in regs.
// Per 128-k tile: wave w owns k-slice [w*32,w*32+32): S^T = K*Q'^T (A from
// LDS K, B from regs), P = 2^S * ss in regs, C->B layout via shfl half-swap,
// O^T partial += V*P (A from LDS V). Cross-wave O reduction once at end.
__global__ __launch_bounds__(256)
void attn_kernel(const u16t* __restrict__ Qb, const u16t* __restrict__ Kb,
                 const u16t* __restrict__ Vt, const float* __restrict__ ssc,
                 u16t* __restrict__ Hout) {
  __shared__ __align__(16) u16t lbuf[128 * 64 + 64 * 128];  // 32KB
  u16t* lK = lbuf;
  u16t* lV = lbuf + 128 * 64;
  const int tid = threadIdx.x, lane = tid & 63, w = tid >> 6;
  const int l31 = lane & 31, lh = lane >> 5;
  const int bh = blockIdx.y, q0 = blockIdx.x * 64;
  const size_t hb = (size_t)bh * (SEQ * HDIM);
  const float* ssb = ssc + (size_t)bh * SEQ;

  // Stage Q tile (8KB) through lK, lift B-frags to registers.
#pragma unroll
  for (int i = 0; i < 2; ++i) {
    int c = w * 2 + i;
    GLDS16(Qb + hb + (size_t)q0 * HDIM + c * 512 + lane * 8, &lK[c * 512]);
  }
  __syncthreads();
  short8 qf[2][4];
#pragma unroll
  for (int qb = 0; qb < 2; ++qb)
#pragma unroll
    for (int t = 0; t < 4; ++t) {
      int r = qb * 32 + l31;
      qf[qb][t] = *(const short8*)&lK[r * 64 + swz(r, t * 16 + lh * 8)];
    }
  __syncthreads();

  floatx16 oacc[2][2];  // [db][qb] partial O^T over this wave's k-slices
#pragma unroll
  for (int a = 0; a < 2; ++a)
#pragma unroll
    for (int b = 0; b < 2; ++b)
#pragma unroll
      for (int r = 0; r < 16; ++r) oacc[a][b][r] = 0.f;

  for (int kt = 0; kt < 16; ++kt) {
    const int k0 = kt * 128;
#pragma unroll
    for (int i = 0; i < 4; ++i) {
      int c = w * 4 + i;
      GLDS16(Kb + hb + (size_t)k0 * HDIM + c * 512 + lane * 8, &lK[c * 512]);
    }
#pragma unroll
    for (int i = 0; i < 4; ++i) {
      int c = w * 4 + i;
      int off = c * 1024 + lane * 16;
      int d = off >> 8, ib = off & 255;
      GLDS16(Vt + hb + ((size_t)d << 11) + k0 + (ib >> 1), &lV[c * 512]);
    }
    float4 sv[4];
#pragma unroll
    for (int g = 0; g < 4; ++g)
      sv[g] = *(const float4*)&ssb[k0 + w * 32 + g * 8 + lh * 4];
    __syncthreads();

    short8 kf[4];
#pragma unroll
    for (int t = 0; t < 4; ++t) {
      int r = w * 32 + l31;
      kf[t] = *(const short8*)&lK[r * 64 + swz(r, t * 16 + lh * 8)];
    }

    short8 pfrag[2][2];
#pragma unroll
    for (int qb = 0; qb < 2; ++qb) {
      floatx16 st;
#pragma unroll
      for (int r = 0; r < 16; ++r) st[r] = 0.f;
#pragma unroll
      for (int t = 0; t < 4; ++t) st = MFMA32(kf[t], qf[qb][t], st);
      // st reg r: k_local = (r&3)+8*(r>>2)+4*lh (within wave's 32-k slice)
      unsigned G[8];
#pragma unroll
      for (int g = 0; g < 4; ++g) {
        float p0 = EXP2(st[g * 4 + 0]) * sv[g].x;
        float p1 = EXP2(st[g * 4 + 1]) * sv[g].y;
        float p2 = EXP2(st[g * 4 + 2]) * sv[g].z;
        float p3 = EXP2(st[g * 4 + 3]) * sv[g].w;
        G[g * 2] = pack2(p1, p0);
        G[g * 2 + 1] = pack2(p3, p2);
      }
      // C-layout -> B-operand layout: half-swap lanes l <-> l^32
#pragma unroll
      for (int tt = 0; tt < 2; ++tt) {
        unsigned aA = G[tt * 4 + 0], bA = G[tt * 4 + 1];
        unsigned aB = G[tt * 4 + 2], bB = G[tt * 4 + 3];
        unsigned paA = (unsigned)__shfl_xor((int)aA, 32);
        unsigned pbA = (unsigned)__shfl_xor((int)bA, 32);
        unsigned paB = (unsigned)__shfl_xor((int)aB, 32);
        unsigned pbB = (unsigned)__shfl_xor((int)bB, 32);
        union { unsigned u[4]; short8 s; } t4;
        t4.u[0] = lh ? paB : aA;
        t4.u[1] = lh ? pbB : bA;
        t4.u[2] = lh ? aB : paA;
        t4.u[3] = lh ? bB : pbA;
        pfrag[qb][tt] = t4.s;
      }
    }
    // O^T[d][q] partial += V * P over this wave's k-slice
#pragma unroll
    for (int db = 0; db < 2; ++db) {
      short8 vf[2];
#pragma unroll
      for (int tt = 0; tt < 2; ++tt) {
        int r = db * 32 + l31;
        vf[tt] = *(const short8*)&lV[r * 128 + swz(r, w * 32 + tt * 16 + lh * 8)];
      }
#pragma unroll
      for (int qb = 0; qb < 2; ++qb)
#pragma unroll
        for (int tt = 0; tt < 2; ++tt)
          oacc[db][qb] = MFMA32(vf[tt], pfrag[qb][tt], oacc[db][qb]);
    }
    __syncthreads();
  }

  // Cross-wave reduction of O^T partials via LDS (reuse lbuf as 2 f32 maps).
  float* R0 = (float*)lbuf;                 // [q][d] 64x64 f32, sw4-swizzled
  float* R1 = (float*)(lbuf + 128 * 64);
  if (w < 2) {
    float* R = w ? R1 : R0;
#pragma unroll
    for (int db = 0; db < 2; ++db)
#pragma unroll
      for (int qb = 0; qb < 2; ++qb)
#pragma unroll
        for (int g = 0; g < 4; ++g) {
          int q = qb * 32 + l31, d = db * 32 + g * 8 + lh * 4;
          float4 v;
          v.x = oacc[db][qb][g * 4 + 0]; v.y = oacc[db][qb][g * 4 + 1];
          v.z = oacc[db][qb][g * 4 + 2]; v.w = oacc[db][qb][g * 4 + 3];
          *(float4*)&R[q * 64 + sw4(q, d)] = v;
        }
  }
  __syncthreads();
  if (w >= 2) {
    float* R = (w == 3) ? R1 : R0;
#pragma unroll
    for (int db = 0; db < 2; ++db)
#pragma unroll
      for (int qb = 0; qb < 2; ++qb)
#pragma unroll
        for (int g = 0; g < 4; ++g) {
          int q = qb * 32 + l31, d = db * 32 + g * 8 + lh * 4;
          float4* p = (float4*)&R[q * 64 + sw4(q, d)];
          float4 v = *p;
          v.x += oacc[db][qb][g * 4 + 0]; v.y += oacc[db][qb][g * 4 + 1];
          v.z += oacc[db][qb][g * 4 + 2]; v.w += oacc[db][qb][g * 4 + 3];
          *p = v;
        }
  }
  __syncthreads();
  // Final: sum R0+R1, pack, store Hout[b][q][h*64+d] (swizzled key q&7).
  const int b = bh >> 4, h = bh & 15;
  const int q = tid >> 2, dc = (tid & 3) * 16;
  float4 o[4];
#pragma unroll
  for (int i = 0; i < 4; ++i) {
    float4 x = *(const float4*)&R0[q * 64 + sw4(q, dc + i * 4)];
    float4 y = *(const float4*)&R1[q * 64 + sw4(q, dc + i * 4)];
    o[i].x = x.x + y.x; o[i].y = x.y + y.y;
    o[i].z = x.z + y.z; o[i].w = x.w + y.w;
  }
  size_t row = ((size_t)b * SEQ + q0 + q) * DMODEL + h * HDIM;
  uint4 u0, u1;
  u0.x = pack2(o[0].y, o[0].x); u0.y = pack2(o[0].w, o[0].z);
  u0.z = pack2(o[1].y, o[1].x); u0.w = pack2(o[1].w, o[1].z);
  u1.x = pack2(o[2].y, o[2].x); u1.y = pack2(o[2].w, o[2].z);
  u1.z = pack2(o[3].y, o[3].x); u1.w = pack2(o[3].w, o[3].z);
  *(uint4*)&Hout[row + swz(q, dc)] = u0;
  *(uint4*)&Hout[row + swz(q, dc + 8)] = u1;
}

// ---------------------------------------------------------------------------
extern "C" void kernel_launch(void* const* d_in, const int* in_sizes, int n_in,
                              void* d_out, int out_size, void* d_ws, size_t ws_size,
                              hipStream_t stream) {
  (void)in_sizes; (void)n_in; (void)out_size; (void)ws_size;
  const float* queries = (const float*)d_in[0];
  const float* keys    = (const float*)d_in[1];
  const float* values  = (const float*)d_in[2];
  const float* Wq = (const float*)d_in[3];
  const float* bq = (const float*)d_in[4];
  const float* Wk = (const float*)d_in[5];
  const float* bk = (const float*)d_in[6];
  const float* Wv = (const float*)d_in[7];
  const float* bv = (const float*)d_in[8];
  const float* Wo = (const float*)d_in[9];
  const float* bo = (const float*)d_in[10];

  char* ws = (char*)d_ws;
  const size_t MB = 1024 * 1024;
  u16t* Qb   = (u16t*)(ws + 0 * MB);    // [b,h,s,d] bf16 swz (x 1/ln2)
  u16t* Kb   = (u16t*)(ws + 16 * MB);   // [b,h,s,d] bf16 swz
  u16t* Vt   = (u16t*)(ws + 32 * MB);   // [b,h,d,s] bf16 swz (unscaled)
  u16t* Hout = (u16t*)(ws + 48 * MB);   // [b,s,dm] bf16 swz
  u16t* wqt  = (u16t*)(ws + 64 * MB);
  u16t* wkt  = (u16t*)(ws + 66 * MB);
  u16t* wvt  = (u16t*)(ws + 68 * MB);
  u16t* wot  = (u16t*)(ws + 70 * MB);
  float* ssc = (float*)(ws + 72 * MB);  // [bh][s] 1/(8*sum 2^S')

  wt_kernel<<<2048, 256, 0, stream>>>(Wq, Wk, Wv, Wo, wqt, wkt, wvt, wot);

  proj_qkv<<<dim3(8, 64, 3), 256, 0, stream>>>(
      queries, keys, values, wqt, wkt, wvt, bq, bk, bv, Qb, Kb, Vt);

  stats_kernel<<<dim3(8, 64), 256, 0, stream>>>(Qb, Kb, ssc);

  attn_kernel<<<dim3(32, 64), 256, 0, stream>>>(Qb, Kb, Vt, ssc, Hout);

  proj_out<<<dim3(8, 64), 256, 0, stream>>>(Hout, wot, bo, (float*)d_out);
}

// Round 5
// 463.920 us; speedup vs baseline: 1.0721x; 1.0721x over previous
//
#include <hip/hip_runtime.h>
#include <cstddef>

// ============================================================================
// MaskedMultiHeadAttention (B=4,S=2048,DM=1024,H=16,HD=64), faithful to ref:
//   softmax over the QUERY axis (axis=2), then /sqrt(HD); mask is a no-op.
// Round 5: attn reverted to the R3 structure (16x16x32, P LDS roundtrip) with
// ss applied in attn; projections all use the m97 global_load_lds bf16 path
// fed by a standalone fp32->bf16-swizzled conversion pass. Conversion scratch
// lives in d_out (dead until proj_out) + the Hout slot: ws stays 73 MB.
// 7 dispatches: wt, cvt3, proj_qkv(z=3), stats, attn, proj_out.
// ============================================================================

typedef unsigned short u16t;
typedef __attribute__((ext_vector_type(8))) short short8;
typedef __attribute__((ext_vector_type(4))) float floatx4;
typedef __attribute__((ext_vector_type(16))) float floatx16;

#define MFMA16(a, b, c) __builtin_amdgcn_mfma_f32_16x16x32_bf16((a), (b), (c), 0, 0, 0)
#define MFMA32(a, b, c) __builtin_amdgcn_mfma_f32_32x32x16_bf16((a), (b), (c), 0, 0, 0)
#define GLDS16(g, l)                                                        \
  __builtin_amdgcn_global_load_lds(                                         \
      (const __attribute__((address_space(1))) unsigned int*)(g),           \
      (__attribute__((address_space(3))) unsigned int*)(l), 16, 0, 0)

#if __has_builtin(__builtin_amdgcn_exp2f)
#define EXP2(x) __builtin_amdgcn_exp2f(x)
#else
#define EXP2(x) __expf(0.69314718f * (x))
#endif

static __device__ __forceinline__ u16t f2bf(float f) {
  union { float f; unsigned u; } v; v.f = f;
  unsigned r = v.u + 0x7FFFu + ((v.u >> 16) & 1u);  // RNE
  return (u16t)(r >> 16);
}
// Pack two f32 -> two bf16 (round-half-up) in one v_perm: hi<<16 | lo.
static __device__ __forceinline__ unsigned pack2(float hi, float lo) {
  union { float f; unsigned u; } a, b; a.f = hi; b.f = lo;
  return __builtin_amdgcn_perm(a.u + 0x8000u, b.u + 0x8000u, 0x07060302u);
}

// XOR swizzle within a 64/128-elem row block (8-elem groups).
static __device__ __forceinline__ int swz(int row, int col) {
  return (((col >> 3) ^ (row & 7)) << 3) | (col & 7);
}

#define SEQ    2048
#define NHEAD  16
#define HDIM   64
#define DMODEL 1024

// ---------------------------------------------------------------------------
// All four W [1024][1024] f32 (in,out) -> WT [n][k-swizzled] bf16, one launch.
__global__ __launch_bounds__(256)
void wt_kernel(const float* __restrict__ W0, const float* __restrict__ W1,
               const float* __restrict__ W2, const float* __restrict__ W3,
               u16t* __restrict__ T0, u16t* __restrict__ T1,
               u16t* __restrict__ T2, u16t* __restrict__ T3) {
  int id = blockIdx.x * 256 + threadIdx.x;  // 2048 blocks
  int wsel = id >> 17;
  int r = id & 131071;
  int n = r & 1023;
  int k0 = (r >> 10) << 3;
  const float* W = wsel == 0 ? W0 : wsel == 1 ? W1 : wsel == 2 ? W2 : W3;
  u16t* T = wsel == 0 ? T0 : wsel == 1 ? T1 : wsel == 2 ? T2 : T3;
  const float* src = W + (size_t)k0 * 1024 + n;
  float f[8];
#pragma unroll
  for (int i = 0; i < 8; ++i) f[i] = src[(size_t)i * 1024];
  uint4 p;
  p.x = pack2(f[1], f[0]); p.y = pack2(f[3], f[2]);
  p.z = pack2(f[5], f[4]); p.w = pack2(f[7], f[6]);
  *(uint4*)&T[(size_t)n * 1024 + (k0 & ~63) + swz(n, k0 & 63)] = p;
}

// ---------------------------------------------------------------------------
// queries/keys/values [8192][1024] fp32 -> bf16 [row][k-swizzled] (memory-
// bound; feeds the GLDS16 fast path in proj_qkv). One dispatch, 3 tensors.
__global__ __launch_bounds__(256)
void cvt_kernel(const float* __restrict__ S0, const float* __restrict__ S1,
                const float* __restrict__ S2,
                u16t* __restrict__ D0, u16t* __restrict__ D1,
                u16t* __restrict__ D2) {
  int id = blockIdx.x * 256 + threadIdx.x;  // 12288 blocks -> 3*2^20 ids
  int wsel = id >> 20;
  int r = id & 1048575;
  int row = r >> 7;
  int k0 = (r & 127) << 3;
  const float* S = wsel == 0 ? S0 : wsel == 1 ? S1 : S2;
  u16t* D = wsel == 0 ? D0 : wsel == 1 ? D1 : D2;
  const float* src = S + (size_t)row * 1024 + k0;
  float4 a = *(const float4*)src;
  float4 b = *(const float4*)(src + 4);
  uint4 p;
  p.x = pack2(a.y, a.x); p.y = pack2(a.w, a.z);
  p.z = pack2(b.y, b.x); p.w = pack2(b.w, b.z);
  *(uint4*)&D[(size_t)row * 1024 + (k0 & ~63) + swz(row, k0 & 63)] = p;
}

// ---------------------------------------------------------------------------
// QKV projections, one dispatch (z = 0:Q, 1:K, 2:V). A bf16-swizzled via
// GLDS16 (m97 fast path), B = pre-swizzled WT via GLDS16. 16x16x32 MFMA.
// z<2: out bf16 swizzled [b,h,s,d] (Q scaled by 1/ln2); z=2: [b,h,d,s].
__global__ __launch_bounds__(256)
void proj_qkv(const u16t* __restrict__ Aq, const u16t* __restrict__ Ak,
              const u16t* __restrict__ Av,
              const u16t* __restrict__ Wq, const u16t* __restrict__ Wk,
              const u16t* __restrict__ Wv,
              const float* __restrict__ Bq, const float* __restrict__ Bk,
              const float* __restrict__ Bv,
              u16t* __restrict__ Oq, u16t* __restrict__ Ok,
              u16t* __restrict__ Ov) {
  constexpr int K = 1024;
  __shared__ __align__(16) u16t lA[128 * 64];
  __shared__ __align__(16) u16t lB[128 * 64];
  const int z = blockIdx.z;
  const u16t* Ap = z == 0 ? Aq : z == 1 ? Ak : Av;
  const u16t* BT = z == 0 ? Wq : z == 1 ? Wk : Wv;
  const float* bias = z == 0 ? Bq : z == 1 ? Bk : Bv;
  u16t* Cp = z == 0 ? Oq : z == 1 ? Ok : Ov;
  const float qsc = z == 0 ? 1.44269504f : 1.0f;
  const int tid = threadIdx.x;
  const int lane = tid & 63, w = tid >> 6;
  const int wm = w >> 1, wn = w & 1;
  const int lrow = lane & 15, lq = lane >> 4;
  const int m0 = blockIdx.y * 128, n0 = blockIdx.x * 128;

  floatx4 acc[4][4];
#pragma unroll
  for (int i = 0; i < 4; ++i)
#pragma unroll
    for (int j = 0; j < 4; ++j) acc[i][j] = {0.f, 0.f, 0.f, 0.f};

  for (int kb = 0; kb < K; kb += 64) {
#pragma unroll
    for (int i = 0; i < 4; ++i) {
      int chunk = w * 4 + i;
      int off = chunk * 1024 + lane * 16;
      int r = off >> 7, ib = off & 127;
      GLDS16(Ap + (size_t)(m0 + r) * K + kb + (ib >> 1), &lA[chunk * 512]);
    }
#pragma unroll
    for (int i = 0; i < 4; ++i) {
      int chunk = w * 4 + i;
      int off = chunk * 1024 + lane * 16;
      int r = off >> 7, ib = off & 127;
      GLDS16(BT + (size_t)(n0 + r) * K + kb + (ib >> 1), &lB[chunk * 512]);
    }
    __syncthreads();
#pragma unroll
    for (int kk = 0; kk < 2; ++kk) {
      short8 af[4], bfr[4];
#pragma unroll
      for (int t = 0; t < 4; ++t) {
        int ar = wm * 64 + t * 16 + lrow;
        af[t] = *(const short8*)&lA[ar * 64 + swz(ar, kk * 32 + lq * 8)];
      }
#pragma unroll
      for (int t = 0; t < 4; ++t) {
        int br = wn * 64 + t * 16 + lrow;
        bfr[t] = *(const short8*)&lB[br * 64 + swz(br, kk * 32 + lq * 8)];
      }
#pragma unroll
      for (int i = 0; i < 4; ++i)
#pragma unroll
        for (int j = 0; j < 4; ++j)
          acc[i][j] = MFMA16(af[i], bfr[j], acc[i][j]);
    }
    __syncthreads();
  }

  float bvv[4];
#pragma unroll
  for (int j = 0; j < 4; ++j) bvv[j] = bias[n0 + wn * 64 + j * 16 + lrow];
  const int h = (n0 + wn * 64) >> 6;
#pragma unroll
  for (int i = 0; i < 4; ++i) {
#pragma unroll
    for (int r = 0; r < 4; ++r) {
      int rg = m0 + wm * 64 + i * 16 + lq * 4 + r;
      int b = rg >> 11, s = rg & 2047;
      size_t bh = (size_t)(b * NHEAD + h);
#pragma unroll
      for (int j = 0; j < 4; ++j) {
        int cg = n0 + wn * 64 + j * 16 + lrow;
        int d = cg & 63;
        float v = (acc[i][j][r] + bvv[j]) * qsc;
        if (z < 2)
          Cp[(bh * SEQ + s) * HDIM + swz(s, d)] = f2bf(v);
        else
          Cp[(bh * HDIM + d) * SEQ + (s & ~127) + swz(d, s & 127)] = f2bf(v);
      }
    }
  }
}

// ---------------------------------------------------------------------------
// Out projection: A = Hout bf16 swizzled (GLDS), out fp32 flat [m][n].
__global__ __launch_bounds__(256)
void proj_out(const u16t* __restrict__ Ap, const u16t* __restrict__ BT,
              const float* __restrict__ bias, float* __restrict__ Cp) {
  constexpr int K = 1024;
  __shared__ __align__(16) u16t lA[128 * 64];
  __shared__ __align__(16) u16t lB[128 * 64];
  const int tid = threadIdx.x;
  const int lane = tid & 63, w = tid >> 6;
  const int wm = w >> 1, wn = w & 1;
  const int lrow = lane & 15, lq = lane >> 4;
  const int m0 = blockIdx.y * 128, n0 = blockIdx.x * 128;

  floatx4 acc[4][4];
#pragma unroll
  for (int i = 0; i < 4; ++i)
#pragma unroll
    for (int j = 0; j < 4; ++j) acc[i][j] = {0.f, 0.f, 0.f, 0.f};

  for (int kb = 0; kb < K; kb += 64) {
#pragma unroll
    for (int i = 0; i < 4; ++i) {
      int chunk = w * 4 + i;
      int off = chunk * 1024 + lane * 16;
      int r = off >> 7, ib = off & 127;
      GLDS16(Ap + (size_t)(m0 + r) * K + kb + (ib >> 1), &lA[chunk * 512]);
    }
#pragma unroll
    for (int i = 0; i < 4; ++i) {
      int chunk = w * 4 + i;
      int off = chunk * 1024 + lane * 16;
      int r = off >> 7, ib = off & 127;
      GLDS16(BT + (size_t)(n0 + r) * K + kb + (ib >> 1), &lB[chunk * 512]);
    }
    __syncthreads();
#pragma unroll
    for (int kk = 0; kk < 2; ++kk) {
      short8 af[4], bfr[4];
#pragma unroll
      for (int t = 0; t < 4; ++t) {
        int ar = wm * 64 + t * 16 + lrow;
        af[t] = *(const short8*)&lA[ar * 64 + swz(ar, kk * 32 + lq * 8)];
      }
#pragma unroll
      for (int t = 0; t < 4; ++t) {
        int br = wn * 64 + t * 16 + lrow;
        bfr[t] = *(const short8*)&lB[br * 64 + swz(br, kk * 32 + lq * 8)];
      }
#pragma unroll
      for (int i = 0; i < 4; ++i)
#pragma unroll
        for (int j = 0; j < 4; ++j)
          acc[i][j] = MFMA16(af[i], bfr[j], acc[i][j]);
    }
    __syncthreads();
  }

  float bvv[4];
#pragma unroll
  for (int j = 0; j < 4; ++j) bvv[j] = bias[n0 + wn * 64 + j * 16 + lrow];
#pragma unroll
  for (int i = 0; i < 4; ++i)
#pragma unroll
    for (int r = 0; r < 4; ++r) {
      int rg = m0 + wm * 64 + i * 16 + lq * 4 + r;
#pragma unroll
      for (int j = 0; j < 4; ++j) {
        int cg = n0 + wn * 64 + j * 16 + lrow;
        Cp[(size_t)rg * 1024 + cg] = acc[i][j][r] + bvv[j];
      }
    }
}

// ---------------------------------------------------------------------------
// Column-softmax stats, exp2 domain (Q pre-scaled 1/ln2, S' bounded):
//   ss[k] = 1/(8 * sum_q 2^(S'[q,k])).  32x32x16 MFMA, K frags in registers.
// Grid (8,64): block = 256 cols; wave w owns cols [w*64, w*64+64).
__global__ __launch_bounds__(256)
void stats_kernel(const u16t* __restrict__ Qb, const u16t* __restrict__ Kb,
                  float* __restrict__ ss) {
  __shared__ __align__(16) u16t lK[256 * 64];  // 32KB
  __shared__ __align__(16) u16t lQ[128 * 64];  // 16KB
  const int tid = threadIdx.x, lane = tid & 63, w = tid >> 6;
  const int l31 = lane & 31, lh = lane >> 5;
  const int bh = blockIdx.y;
  const int c0 = blockIdx.x * 256;
  const u16t* Kbase = Kb + (size_t)bh * (SEQ * HDIM);
  const u16t* Qbase = Qb + (size_t)bh * (SEQ * HDIM);

#pragma unroll
  for (int i = 0; i < 8; ++i) {
    int c = w * 8 + i;
    GLDS16(Kbase + (size_t)c0 * HDIM + c * 512 + lane * 8, &lK[c * 512]);
  }

  short8 kf[2][4];
  float acc[2][16];
#pragma unroll
  for (int kb = 0; kb < 2; ++kb)
#pragma unroll
    for (int r = 0; r < 16; ++r) acc[kb][r] = 0.f;

  for (int q0 = 0; q0 < SEQ; q0 += 128) {
#pragma unroll
    for (int i = 0; i < 4; ++i) {
      int c = w * 4 + i;
      GLDS16(Qbase + (size_t)q0 * HDIM + c * 512 + lane * 8, &lQ[c * 512]);
    }
    __syncthreads();
    if (q0 == 0) {
#pragma unroll
      for (int kb = 0; kb < 2; ++kb)
#pragma unroll
        for (int t = 0; t < 4; ++t) {
          int r = w * 64 + kb * 32 + l31;
          kf[kb][t] = *(const short8*)&lK[r * 64 + swz(r, t * 16 + lh * 8)];
        }
    }
#pragma unroll
    for (int qb = 0; qb < 4; ++qb) {
      short8 qfr[4];
#pragma unroll
      for (int t = 0; t < 4; ++t) {
        int r = qb * 32 + l31;
        qfr[t] = *(const short8*)&lQ[r * 64 + swz(r, t * 16 + lh * 8)];
      }
#pragma unroll
      for (int kb = 0; kb < 2; ++kb) {
        floatx16 st;
#pragma unroll
        for (int r = 0; r < 16; ++r) st[r] = 0.f;
#pragma unroll
        for (int t = 0; t < 4; ++t) st = MFMA32(kf[kb][t], qfr[t], st);
#pragma unroll
        for (int r = 0; r < 16; ++r) acc[kb][r] += EXP2(st[r]);
      }
    }
    __syncthreads();
  }
#pragma unroll
  for (int kb = 0; kb < 2; ++kb)
#pragma unroll
    for (int r = 0; r < 16; ++r) {
      float v = acc[kb][r];
#pragma unroll
      for (int off = 1; off <= 16; off <<= 1) v += __shfl_xor(v, off);
      acc[kb][r] = v;
    }
  if (l31 == 0) {  // lanes 0 and 32 write (lh selects +4 k offset)
#pragma unroll
    for (int kb = 0; kb < 2; ++kb)
#pragma unroll
      for (int r = 0; r < 16; ++r) {
        int k = c0 + w * 64 + kb * 32 + (r & 3) + 8 * (r >> 2) + 4 * lh;
        ss[(size_t)bh * SEQ + k] = 1.f / (8.f * acc[kb][r]);
      }
  }
}

// ---------------------------------------------------------------------------
// attn (R3 structure): per (b,h, 64-q tile): loop 128-k tiles:
//   S'^T = K*Q'^T (MFMA) -> P = 2^(S')*ss[k] packed via v_perm -> O += P*V
// LDS 32.5KB: Q staged through lKP once, frags kept in registers.
__global__ __launch_bounds__(256)
void attn_kernel(const u16t* __restrict__ Qb, const u16t* __restrict__ Kb,
                 const u16t* __restrict__ Vt, const float* __restrict__ ssc,
                 u16t* __restrict__ Hout) {
  __shared__ __align__(16) u16t lKP[128 * 64];  // Q stage -> K tile -> P tile
  __shared__ __align__(16) u16t lV[64 * 128];   // V^T tile [d][k]
  __shared__ __align__(16) float lS[128];
  const int tid = threadIdx.x, lane = tid & 63, w = tid >> 6;
  const int lrow = lane & 15, lq = lane >> 4;
  const int bh = blockIdx.y, q0 = blockIdx.x * 64;
  const size_t hb = (size_t)bh * (SEQ * HDIM);
  const float* ssb = ssc + (size_t)bh * SEQ;

  // Stage the 8KB Q tile through lKP, lift fragments to registers.
#pragma unroll
  for (int i = 0; i < 2; ++i) {
    int chunk = w * 2 + i;
    GLDS16(Qb + hb + (size_t)q0 * HDIM + chunk * 512 + lane * 8, &lKP[chunk * 512]);
  }
  __syncthreads();
  const int qr = w * 16 + lrow;
  short8 bq0 = *(const short8*)&lKP[qr * 64 + swz(qr, lq * 8)];
  short8 bq1 = *(const short8*)&lKP[qr * 64 + swz(qr, lq * 8 + 32)];
  __syncthreads();  // everyone has Q frags before K staging overwrites lKP

  floatx4 ao[4];
#pragma unroll
  for (int t = 0; t < 4; ++t) ao[t] = {0.f, 0.f, 0.f, 0.f};

  for (int kt = 0; kt < 16; ++kt) {
    const int k0 = kt * 128;
#pragma unroll
    for (int i = 0; i < 4; ++i) {
      int chunk = w * 4 + i;
      GLDS16(Kb + hb + (size_t)k0 * HDIM + chunk * 512 + lane * 8, &lKP[chunk * 512]);
    }
#pragma unroll
    for (int i = 0; i < 4; ++i) {
      int chunk = w * 4 + i;
      int off = chunk * 1024 + lane * 16;
      int d = off >> 8, ib = off & 255;
      GLDS16(Vt + hb + ((size_t)d << 11) + k0 + (ib >> 1), &lV[chunk * 512]);
    }
    if (tid < 32) *(float4*)&lS[tid * 4] = *(const float4*)&ssb[k0 + tid * 4];
    __syncthreads();

    // S'^T = K Q'^T : lane holds St[k=nt*16+lq*4+r][q=w*16+lrow]
    floatx4 st[8];
#pragma unroll
    for (int nt = 0; nt < 8; ++nt) {
      int kr = nt * 16 + lrow;
      short8 ak0 = *(const short8*)&lKP[kr * 64 + swz(kr, lq * 8)];
      short8 ak1 = *(const short8*)&lKP[kr * 64 + swz(kr, lq * 8 + 32)];
      floatx4 a = {0.f, 0.f, 0.f, 0.f};
      a = MFMA16(ak0, bq0, a);
      a = MFMA16(ak1, bq1, a);
      st[nt] = a;
    }
    __syncthreads();  // all waves done reading lKP(K) before P overwrites it

    // P[q][k] = 2^(S')*ss[k]: 4 exp2 + 4 mul + 2 perm + b64 write per 4 elems
#pragma unroll
    for (int nt = 0; nt < 8; ++nt) {
      float4 sv = *(const float4*)&lS[nt * 16 + lq * 4];
      float p0 = EXP2(st[nt][0]) * sv.x;
      float p1 = EXP2(st[nt][1]) * sv.y;
      float p2 = EXP2(st[nt][2]) * sv.z;
      float p3 = EXP2(st[nt][3]) * sv.w;
      uint2 pk; pk.x = pack2(p1, p0); pk.y = pack2(p3, p2);
      *(uint2*)&lKP[qr * 128 + swz(qr, nt * 16 + lq * 4)] = pk;
    }
    // O += P * V' (wave reads only its own P rows -> no barrier needed)
    {
      short8 ap[4];
#pragma unroll
      for (int kk = 0; kk < 4; ++kk)
        ap[kk] = *(const short8*)&lKP[qr * 128 + swz(qr, kk * 32 + lq * 8)];
#pragma unroll
      for (int nt = 0; nt < 4; ++nt) {
        int vr = nt * 16 + lrow;
#pragma unroll
        for (int kk = 0; kk < 4; ++kk) {
          short8 bv = *(const short8*)&lV[vr * 128 + swz(vr, kk * 32 + lq * 8)];
          ao[nt] = MFMA16(ap[kk], bv, ao[nt]);
        }
      }
    }
    __syncthreads();  // before next iteration restages lKP/lV
  }

  // Hout[b][q][h*64+d], swizzled (key q&7) for proj_out's GLDS16 staging
  const int b = bh >> 4, h = bh & 15;
#pragma unroll
  for (int nt = 0; nt < 4; ++nt) {
    int d = nt * 16 + lrow;
#pragma unroll
    for (int r = 0; r < 4; ++r) {
      int q = q0 + w * 16 + lq * 4 + r;
      Hout[((size_t)b * SEQ + q) * DMODEL + h * HDIM + swz(q, d)] = f2bf(ao[nt][r]);
    }
  }
}

// ---------------------------------------------------------------------------
extern "C" void kernel_launch(void* const* d_in, const int* in_sizes, int n_in,
                              void* d_out, int out_size, void* d_ws, size_t ws_size,
                              hipStream_t stream) {
  (void)in_sizes; (void)n_in; (void)out_size; (void)ws_size;
  const float* queries = (const float*)d_in[0];
  const float* keys    = (const float*)d_in[1];
  const float* values  = (const float*)d_in[2];
  const float* Wq = (const float*)d_in[3];
  const float* bq = (const float*)d_in[4];
  const float* Wk = (const float*)d_in[5];
  const float* bk = (const float*)d_in[6];
  const float* Wv = (const float*)d_in[7];
  const float* bv = (const float*)d_in[8];
  const float* Wo = (const float*)d_in[9];
  const float* bo = (const float*)d_in[10];

  char* ws = (char*)d_ws;
  const size_t MB = 1024 * 1024;
  u16t* Qb   = (u16t*)(ws + 0 * MB);    // [b,h,s,d] bf16 swz (x 1/ln2)
  u16t* Kb   = (u16t*)(ws + 16 * MB);   // [b,h,s,d] bf16 swz
  u16t* Vt   = (u16t*)(ws + 32 * MB);   // [b,h,d,s] bf16 swz
  u16t* Hout = (u16t*)(ws + 48 * MB);   // Abf_v scratch, then attn output
  u16t* wqt  = (u16t*)(ws + 64 * MB);
  u16t* wkt  = (u16t*)(ws + 66 * MB);
  u16t* wvt  = (u16t*)(ws + 68 * MB);
  u16t* wot  = (u16t*)(ws + 70 * MB);
  float* ssc = (float*)(ws + 72 * MB);  // [bh][s] 1/(8*sum 2^S')
  // d_out (32MB fp32, dead until proj_out) hosts the Q/K bf16 conversions.
  u16t* Aq = (u16t*)d_out;
  u16t* Ak = (u16t*)((char*)d_out + 16 * MB);
  u16t* Av = Hout;

  wt_kernel<<<2048, 256, 0, stream>>>(Wq, Wk, Wv, Wo, wqt, wkt, wvt, wot);

  cvt_kernel<<<12288, 256, 0, stream>>>(queries, keys, values, Aq, Ak, Av);

  proj_qkv<<<dim3(8, 64, 3), 256, 0, stream>>>(
      Aq, Ak, Av, wqt, wkt, wvt, bq, bk, bv, Qb, Kb, Vt);

  stats_kernel<<<dim3(8, 64), 256, 0, stream>>>(Qb, Kb, ssc);

  attn_kernel<<<dim3(32, 64), 256, 0, stream>>>(Qb, Kb, Vt, ssc, Hout);

  proj_out<<<dim3(8, 64), 256, 0, stream>>>(Hout, wot, bo, (float*)d_out);
}